// Round 11
// baseline (331.879 us; speedup 1.0000x reference)
//
#include <hip/hip_runtime.h>
#include <hip/hip_bf16.h>

#define NB 2
#define NL 4096
#define ND 512
#define NH 8
#define NDK 64
#define NM (NB * NL)   // 8192
#define QSCALE 0.18033688011112042f  // 0.125 * log2(e)

typedef short bf16x8_t __attribute__((ext_vector_type(8)));
typedef float f32x4_t __attribute__((ext_vector_type(4)));

// fp32 -> bf16 bits, round-to-nearest-even
static __device__ __forceinline__ unsigned short f2bs(float f) {
  union { float f; unsigned u; } c; c.f = f;
  unsigned r = c.u + 0x7fffu + ((c.u >> 16) & 1u);
  return (unsigned short)(r >> 16);
}
static __device__ __forceinline__ float bs2f(unsigned short s) {
  union { unsigned u; float f; } c; c.u = ((unsigned)s) << 16; return c.f;
}
static __device__ __forceinline__ unsigned pk_bf16(float a, float b) {
  union { __hip_bfloat162 h; unsigned u; } c;
  c.h = __float22bfloat162_rn(make_float2(a, b));
  return c.u;
}
// hardware packed f32->bf16 (RNE), single VOP3 instruction
static __device__ __forceinline__ unsigned cvt_pk_hw(float a, float b) {
  unsigned r;
  asm("v_cvt_pk_bf16_f32 %0, %1, %2" : "=v"(r) : "v"(a), "v"(b));
  return r;
}
// split fp32 pair -> packed bf16 hi-word + lo-word (residual), RNE.
static __device__ __forceinline__ void split_pk(float a, float b,
                                                unsigned& hw, unsigned& lw) {
  const unsigned short ha = f2bs(a), hb = f2bs(b);
  hw = (unsigned)ha | ((unsigned)hb << 16);
  lw = (unsigned)f2bs(a - bs2f(ha)) | ((unsigned)f2bs(b - bs2f(hb)) << 16);
}

// ---------- pre-pass: W[k][n] fp32 -> transposed hi/lo bf16 planes [n][k] ----------
struct WArgs {
  const float* W[4];
  unsigned short* Th[4];
  unsigned short* Tl[4];
};
__global__ __launch_bounds__(256)
void wsplit_kernel(WArgs a)
{
  const int z = blockIdx.z;
  const float* __restrict__ W = a.W[z];
  const int tid = threadIdx.x;
  const int n = blockIdx.x * 64 + (tid & 63);
  const int kb = blockIdx.y * 64 + (tid >> 6) * 16;
  unsigned short h[16], l[16];
#pragma unroll
  for (int u = 0; u < 16; ++u) {
    const float x = W[(size_t)(kb + u) * ND + n];
    h[u] = f2bs(x);
    l[u] = f2bs(x - bs2f(h[u]));
  }
  unsigned wh[8], wl[8];
#pragma unroll
  for (int p = 0; p < 8; ++p) {
    wh[p] = (unsigned)h[2 * p] | ((unsigned)h[2 * p + 1] << 16);
    wl[p] = (unsigned)l[2 * p] | ((unsigned)l[2 * p + 1] << 16);
  }
  unsigned short* th = a.Th[z] + (size_t)n * ND + kb;
  unsigned short* tl = a.Tl[z] + (size_t)n * ND + kb;
  *(uint4*)th = make_uint4(wh[0], wh[1], wh[2], wh[3]);
  *(uint4*)(th + 8) = make_uint4(wh[4], wh[5], wh[6], wh[7]);
  *(uint4*)tl = make_uint4(wl[0], wl[1], wl[2], wl[3]);
  *(uint4*)(tl + 8) = make_uint4(wl[4], wl[5], wl[6], wl[7]);
}

// ---------- split-bf16 MFMA GEMM core, 128 x (NJ*16) tile, BK=32, reg prefetch ----------
// LDS arena PASSED IN by the kernel shell (single allocation shared by all
// inlined instantiations -- R9/R10 lesson: per-instantiation static __shared__
// arrays SUM). Layout (shorts):
//   [AH 128*36][AL 128*36 iff ASPLIT][BHs NJ*16*36][BLs NJ*16*36]
// proj (no AL, NJ=8): 13824 shorts = 27648 B; out (AL, NJ=4): same 27648 B.
// B is REG-STAGED into padded [36] rows (72B stride -> all 16 banks hit on
// frag reads). R9/R10's gld_lds B forced unpadded 64B rows -> 8-way read
// conflicts -> slower despite cheaper staging. Padding wins here.
// A source: AFP32 (fp32, cvt in-stage, fuses round3) | AMERGE ((op0+op1)/
// (l0+l1) split hi/lo in-stage, fuses merge) | bf16 planes.
// ASPLIT: 3-term (Ahi.Bhi + Ahi.Blo + Alo.Bhi); else 2-term.
// NOTE (rule #20): epilogue p-loops MUST be fully unrolled -- a runtime p
// feeding acc[] indices demotes the accumulator array to scratch (R6).
// OUTMODE: 0 = bf16 head layout; 1 = fp32 flat; 2 = bf16 transposed head.
template <bool ASPLIT, int NJ, int OUTMODE, int WI, int WJ, bool AFP32, bool AMERGE>
__device__ __forceinline__ void gemm_core(
    const void* __restrict__ Ahi_, const unsigned short* __restrict__ Alo,
    const unsigned short* __restrict__ Bh, const unsigned short* __restrict__ Bl,
    const float* __restrict__ bias, unsigned short* __restrict__ outH,
    float* __restrict__ outF, int m0, int n0, float scale,
    const float* __restrict__ opA, const float* __restrict__ lpA,
    unsigned short* sm)
{
  static_assert(!(ASPLIT && AFP32), "unsupported combo");
  static_assert(!(AFP32 && AMERGE), "unsupported combo");
  constexpr int WGC = NJ / WJ;                 // wave-grid cols
  static_assert((4 / WGC) * WI * 16 == 128, "wave grid must tile 128 rows");
  static_assert(OUTMODE == 1 || (WI == 4 && WJ == 4 && WGC == 2),
                "epilogues 0/2 assume 2x2 wave grid");

  constexpr int AELEMS = 128 * 36;
  constexpr int BELEMS = NJ * 16 * 36;
  unsigned short (*AH)[36] = (unsigned short(*)[36])sm;
  unsigned short (*AL)[36] = (unsigned short(*)[36])(sm + AELEMS);  // iff ASPLIT
  unsigned short (*BHs)[36] =
      (unsigned short(*)[36])(sm + AELEMS + (ASPLIT ? AELEMS : 0));
  unsigned short (*BLs)[36] =
      (unsigned short(*)[36])(sm + AELEMS + (ASPLIT ? AELEMS : 0) + BELEMS);

  const int tid = threadIdx.x;
  const int lane = tid & 63, w = tid >> 6;
  const int m = lane & 15, quad = lane >> 4;
  const int wr = w / WGC, wc = w % WGC;
  const int r = tid >> 1, hf = (tid & 1) * 16;
  const int rb = (NJ == 8) ? (tid >> 1) : (tid >> 2);
  const int cb = (NJ == 8) ? ((tid & 1) * 16) : ((tid & 3) * 8);

  const unsigned short* aRow = nullptr;
  const float* aRowF = nullptr;
  if constexpr (AFP32)
    aRowF = (const float*)Ahi_ + (size_t)(m0 + r) * ND + hf;
  else if constexpr (!AMERGE)
    aRow = (const unsigned short*)Ahi_ + (size_t)(m0 + r) * ND + hf;
  const unsigned short* alRow =
      (ASPLIT && !AMERGE) ? (Alo + (size_t)(m0 + r) * ND + hf) : nullptr;
  const unsigned short* bhRow = Bh + (size_t)(n0 + rb) * ND + cb;
  const unsigned short* blRow = Bl + (size_t)(n0 + rb) * ND + cb;

  // AMERGE per-thread row decomposition (b, l)
  int abb = 0, all = 0;
  if constexpr (AMERGE) {
    abb = (m0 + r) >> 12;
    all = (m0 + r) & (NL - 1);
  }

  // prefetch k0 = 0
  uint4 ra0, ra1;
  float4 fa0, fa1, fa2, fa3;
  if constexpr (AFP32) {
    fa0 = *(const float4*)(aRowF);
    fa1 = *(const float4*)(aRowF + 4);
    fa2 = *(const float4*)(aRowF + 8);
    fa3 = *(const float4*)(aRowF + 12);
  } else if constexpr (!AMERGE) {
    ra0 = *(const uint4*)(aRow);
    ra1 = *(const uint4*)(aRow + 8);
  }
  uint4 rl0, rl1;
  if constexpr (ASPLIT && !AMERGE) {
    rl0 = *(const uint4*)(alRow);
    rl1 = *(const uint4*)(alRow + 8);
  }
  uint4 rbh0 = *(const uint4*)(bhRow);
  uint4 rbl0 = *(const uint4*)(blRow);
  uint4 rbh1, rbl1;
  if constexpr (NJ == 8) {
    rbh1 = *(const uint4*)(bhRow + 8);
    rbl1 = *(const uint4*)(blRow + 8);
  }

  f32x4_t acc[WI][WJ];
#pragma unroll
  for (int i = 0; i < WI; ++i)
#pragma unroll
    for (int j = 0; j < WJ; ++j) acc[i][j] = (f32x4_t){0.f, 0.f, 0.f, 0.f};

  for (int k0 = 0; k0 < ND; k0 += 32) {
    // AMERGE: issue this slab's global loads BEFORE the barrier (no LDS
    // hazard); latency hides under the previous MFMA phase + barrier.
    float4 a00, a01, a02, a03, a10, a11, a12, a13;
    float li0, li1;
    if constexpr (AMERGE) {
      const int kk = k0 + hf;
      const int head = kk >> 6;
      const int d0 = kk & (NDK - 1);
      const size_t prow = (size_t)(abb * 8 + head) * NL + all;
      const float* p0 = opA + prow * NDK + d0;
      const float* p1 = p0 + (size_t)16 * NL * NDK;
      a00 = *(const float4*)p0;
      a01 = *(const float4*)(p0 + 4);
      a02 = *(const float4*)(p0 + 8);
      a03 = *(const float4*)(p0 + 12);
      a10 = *(const float4*)p1;
      a11 = *(const float4*)(p1 + 4);
      a12 = *(const float4*)(p1 + 8);
      a13 = *(const float4*)(p1 + 12);
      li0 = lpA[prow];
      li1 = lpA[prow + (size_t)16 * NL];
    }
    __syncthreads();
    if constexpr (AMERGE) {
      const float inv = 1.0f / (li0 + li1);
      uint4 uh0, ul0, uh1, ul1;
      split_pk((a00.x + a10.x) * inv, (a00.y + a10.y) * inv, uh0.x, ul0.x);
      split_pk((a00.z + a10.z) * inv, (a00.w + a10.w) * inv, uh0.y, ul0.y);
      split_pk((a01.x + a11.x) * inv, (a01.y + a11.y) * inv, uh0.z, ul0.z);
      split_pk((a01.z + a11.z) * inv, (a01.w + a11.w) * inv, uh0.w, ul0.w);
      split_pk((a02.x + a12.x) * inv, (a02.y + a12.y) * inv, uh1.x, ul1.x);
      split_pk((a02.z + a12.z) * inv, (a02.w + a12.w) * inv, uh1.y, ul1.y);
      split_pk((a03.x + a13.x) * inv, (a03.y + a13.y) * inv, uh1.z, ul1.z);
      split_pk((a03.z + a13.z) * inv, (a03.w + a13.w) * inv, uh1.w, ul1.w);
      *(uint4*)&AH[r][hf] = uh0;
      *(uint4*)&AH[r][hf + 8] = uh1;
      *(uint4*)&AL[r][hf] = ul0;
      *(uint4*)&AL[r][hf + 8] = ul1;
    } else if constexpr (AFP32) {
      uint4 ua0, ua1;
      ua0.x = pk_bf16(fa0.x, fa0.y);
      ua0.y = pk_bf16(fa0.z, fa0.w);
      ua0.z = pk_bf16(fa1.x, fa1.y);
      ua0.w = pk_bf16(fa1.z, fa1.w);
      ua1.x = pk_bf16(fa2.x, fa2.y);
      ua1.y = pk_bf16(fa2.z, fa2.w);
      ua1.z = pk_bf16(fa3.x, fa3.y);
      ua1.w = pk_bf16(fa3.z, fa3.w);
      *(uint4*)&AH[r][hf] = ua0;
      *(uint4*)&AH[r][hf + 8] = ua1;
    } else {
      *(uint4*)&AH[r][hf] = ra0;
      *(uint4*)&AH[r][hf + 8] = ra1;
    }
    if constexpr (ASPLIT && !AMERGE) {
      *(uint4*)&AL[r][hf] = rl0;
      *(uint4*)&AL[r][hf + 8] = rl1;
    }
    *(uint4*)&BHs[rb][cb] = rbh0;
    *(uint4*)&BLs[rb][cb] = rbl0;
    if constexpr (NJ == 8) {
      *(uint4*)&BHs[rb][cb + 8] = rbh1;
      *(uint4*)&BLs[rb][cb + 8] = rbl1;
    }
    if (k0 + 32 < ND) {  // prefetch next K-slab (overlaps MFMA below)
      const int kn = k0 + 32;
      if constexpr (AFP32) {
        fa0 = *(const float4*)(aRowF + kn);
        fa1 = *(const float4*)(aRowF + kn + 4);
        fa2 = *(const float4*)(aRowF + kn + 8);
        fa3 = *(const float4*)(aRowF + kn + 12);
      } else if constexpr (!AMERGE) {
        ra0 = *(const uint4*)(aRow + kn);
        ra1 = *(const uint4*)(aRow + kn + 8);
      }
      if constexpr (ASPLIT && !AMERGE) {
        rl0 = *(const uint4*)(alRow + kn);
        rl1 = *(const uint4*)(alRow + kn + 8);
      }
      rbh0 = *(const uint4*)(bhRow + kn);
      rbl0 = *(const uint4*)(blRow + kn);
      if constexpr (NJ == 8) {
        rbh1 = *(const uint4*)(bhRow + kn + 8);
        rbl1 = *(const uint4*)(blRow + kn + 8);
      }
    }
    __syncthreads();

    bf16x8_t ah[WI], al[ASPLIT ? WI : 1];
#pragma unroll
    for (int i = 0; i < WI; ++i) {
      ah[i] = *(const bf16x8_t*)&AH[wr * (WI * 16) + 16 * i + m][quad * 8];
      if constexpr (ASPLIT)
        al[i] = *(const bf16x8_t*)&AL[wr * (WI * 16) + 16 * i + m][quad * 8];
    }
#pragma unroll
    for (int j = 0; j < WJ; ++j) {
      const bf16x8_t bhj = *(const bf16x8_t*)&BHs[16 * (wc * WJ + j) + m][quad * 8];
      const bf16x8_t blj = *(const bf16x8_t*)&BLs[16 * (wc * WJ + j) + m][quad * 8];
#pragma unroll
      for (int i = 0; i < WI; ++i) {
        acc[i][j] = __builtin_amdgcn_mfma_f32_16x16x32_bf16(ah[i], bhj, acc[i][j], 0, 0, 0);
        acc[i][j] = __builtin_amdgcn_mfma_f32_16x16x32_bf16(ah[i], blj, acc[i][j], 0, 0, 0);
        if constexpr (ASPLIT)
          acc[i][j] = __builtin_amdgcn_mfma_f32_16x16x32_bf16(al[i], bhj, acc[i][j], 0, 0, 0);
      }
    }
  }

  if constexpr (OUTMODE == 1) {
#pragma unroll
    for (int i = 0; i < WI; ++i)
#pragma unroll
      for (int rr = 0; rr < 4; ++rr) {
        const int mg = m0 + wr * (WI * 16) + 16 * i + quad * 4 + rr;
#pragma unroll
        for (int j = 0; j < WJ; ++j) {
          const int n = n0 + 16 * (wc * WJ + j) + m;
          outF[(size_t)mg * ND + n] = (acc[i][j][rr] + bias[n]) * scale;
        }
      }
  } else if constexpr (OUTMODE == 0) {
    // head-layout out via LDS bounce (reuse BHs/BLs region as T[32 l][136 n]).
    unsigned short* T = (unsigned short*)BHs;   // 9216 shorts >= 4352
    const int bb = m0 >> 12;
#pragma unroll
    for (int p = 0; p < 4; ++p) {
      __syncthreads();
      if (wr == (p >> 1)) {
#pragma unroll
        for (int i2 = 0; i2 < 2; ++i2) {
          const int i = (p & 1) * 2 + i2;   // compile-time (p unrolled)
#pragma unroll
          for (int j = 0; j < WJ; ++j) {
            const int n = wc * 64 + 16 * j + m;
            const float bv = bias[n0 + n];
#pragma unroll
            for (int rr = 0; rr < 4; ++rr)
              T[(16 * i2 + quad * 4 + rr) * 136 + n] =
                  f2bs((acc[i][j][rr] + bv) * scale);
          }
        }
      }
      __syncthreads();
      const int lr = tid >> 3;        // 0..31 local l-row
      const int seg = tid & 7;        // n-chunk of 16
      const uint4 t0 = *(const uint4*)&T[lr * 136 + seg * 16];
      const uint4 t1 = *(const uint4*)&T[lr * 136 + seg * 16 + 8];
      const int ng = n0 + seg * 16;
      const int h = ng >> 6, d = ng & (NDK - 1);
      const int l = (m0 + p * 32 + lr) & (NL - 1);
      unsigned short* dp = outH + (((size_t)(bb * NH + h)) * NL + l) * NDK + d;
      *(uint4*)dp = t0;
      *(uint4*)(dp + 8) = t1;
    }
  } else {
    // VTRANS via LDS bounce (reuse BHs/BLs region as T[128 n][34 l]).
    unsigned short* T = (unsigned short*)BHs;
    const int bb = m0 >> 12;
    const int lbase = m0 & (NL - 1);
#pragma unroll
    for (int p = 0; p < 4; ++p) {
      __syncthreads();
      if (wr == (p >> 1)) {
#pragma unroll
        for (int i2 = 0; i2 < 2; ++i2) {
          const int i = (p & 1) * 2 + i2;   // compile-time (p unrolled)
#pragma unroll
          for (int j = 0; j < WJ; ++j) {
            const int n = wc * 64 + 16 * j + m;
            const float bv = bias[n0 + n];
            const unsigned w0 = pk_bf16((acc[i][j][0] + bv) * scale,
                                        (acc[i][j][1] + bv) * scale);
            const unsigned w1 = pk_bf16((acc[i][j][2] + bv) * scale,
                                        (acc[i][j][3] + bv) * scale);
            *(uint2*)&T[n * 34 + 16 * i2 + quad * 4] = make_uint2(w0, w1);
          }
        }
      }
      __syncthreads();
      const int n = tid >> 1;
      const int l0 = (tid & 1) * 16;
      const uint4 t0 = *(const uint4*)&T[n * 34 + l0];
      const uint4 t1 = *(const uint4*)&T[n * 34 + l0 + 8];
      const int ng = n0 + n;
      const int h = ng >> 6, d = ng & (NDK - 1);
      unsigned short* dp =
          outH + (((size_t)(bb * NH + h)) * NDK + d) * NL + lbase + 32 * p + l0;
      *(uint4*)dp = t0;
      *(uint4*)(dp + 8) = t1;
    }
  }
}

struct ProjArgs {
  const float* A[3];                // fp32 inputs (round3 fused into staging)
  const unsigned short* Bh[3];
  const unsigned short* Bl[3];
  const float* bias[3];
  unsigned short* out[3];
  float scale[3];
};
// Arena: AH (128*36) + BHs + BLs (2*8*16*36) = 13824 shorts = 27648 B,
// shared by BOTH instantiations -> LDS no longer caps occupancy (3 blocks/CU).
__global__ __launch_bounds__(256, 3)
void gemm_proj_kernel(ProjArgs a)
{
  __shared__ __align__(16) unsigned short sm[128 * 36 + 2 * 8 * 16 * 36];
  const int z = blockIdx.z;
  if (z < 2)
    gemm_core<false, 8, 0, 4, 4, true, false>(
        a.A[z], nullptr, a.Bh[z], a.Bl[z], a.bias[z], a.out[z], nullptr,
        blockIdx.x * 128, blockIdx.y * 128, a.scale[z], nullptr, nullptr, sm);
  else
    gemm_core<false, 8, 2, 4, 4, true, false>(
        a.A[2], nullptr, a.Bh[2], a.Bl[2], a.bias[2], a.out[2], nullptr,
        blockIdx.x * 128, blockIdx.y * 128, a.scale[2], nullptr, nullptr, sm);
}
// out GEMM with fused merge: A = (op0+op1)/(l0+l1), split-bf16 in-stage.
// Arena: AH + AL (2*128*36) + BHs + BLs (2*4*16*36) = 13824 shorts = 27648 B.
__global__ __launch_bounds__(256, 3)
void gemm_out_kernel(const float* __restrict__ opA, const float* __restrict__ lpA,
                     const unsigned short* __restrict__ Bh,
                     const unsigned short* __restrict__ Bl,
                     const float* __restrict__ bias, float* __restrict__ out)
{
  __shared__ __align__(16) unsigned short sm[2 * 128 * 36 + 2 * 4 * 16 * 36];
  gemm_core<true, 4, 1, 2, 4, false, true>(
      nullptr, nullptr, Bh, Bl, bias, nullptr, out,
      blockIdx.x * 128, blockIdx.y * 64, 1.0f, opA, lpA, sm);
}

// ---------- MFMA bf16 flash attention ----------
// 256-q blocks (4 waves x 64 q), 2-way key-split, lane-local P via swapped
// QK^T + permuted MFMA contraction order over keys (no P LDS round-trip).
// DOUBLE-BUFFERED K/V LDS, one barrier per K-tile.
// SOFTWARE-PIPELINED c-blocks: ALL 32 QK MFMAs issued up front into stage
// regs s[4][4] (order pinned by sched_barrier).
// Q pre-scaled by 0.125*log2(e) -> p = exp2(s) via raw v_exp_f32;
// P packing via hardware v_cvt_pk_bf16_f32. l-rowsums via ones-B MFMA.
// V arrives pre-transposed [bh][d][l].
// LDS: unpadded 128B rows + 16B-chunk XOR swizzle (chunk ^= row&7).
__global__ __launch_bounds__(256, 2)
void attn_kernel(const unsigned short* __restrict__ qh, const unsigned short* __restrict__ kh,
                 const unsigned short* __restrict__ vt_g, float* __restrict__ op,
                 float* __restrict__ lp)
{
  __shared__ unsigned short Ks[2][64 * 64];  // [key][d], swizzled
  __shared__ unsigned short Vt[2][64 * 64];  // [d][key], swizzled

  const int tid = threadIdx.x;
  const int w = tid >> 6;
  const int lane = tid & 63;
  const int m = lane & 15;
  const int quad = lane >> 4;
  const int sw = m & 7;                 // read-side swizzle key (row&7 = m&7)

  const int bid = blockIdx.x;
  const int half = bid & 1;
  const int qt = (bid >> 1) & 15;       // 16 q-tiles of 256
  const int bh = bid >> 5;              // b*NH + h
  const int kt0 = half * 32, kt1 = kt0 + 32;
  const unsigned short* qb = qh + (size_t)bh * NL * NDK;
  const unsigned short* kb = kh + (size_t)bh * NL * NDK;
  const unsigned short* vb = vt_g + (size_t)bh * NDK * NL;  // [d][l]

  // Q fragments: 64 q rows per wave (4 m-tiles of 16), held in registers.
  bf16x8_t aq[4][2];
#pragma unroll
  for (int mt = 0; mt < 4; ++mt) {
    const unsigned short* qsrc =
        qb + (size_t)(qt * 256 + w * 64 + mt * 16 + m) * NDK + quad * 8;
    aq[mt][0] = *(const bf16x8_t*)(qsrc);
    aq[mt][1] = *(const bf16x8_t*)(qsrc + 32);
  }

  const short ob = (short)0x3F80;
  const bf16x8_t ones = {ob, ob, ob, ob, ob, ob, ob, ob};

  f32x4_t o[4][4];
#pragma unroll
  for (int mt = 0; mt < 4; ++mt)
#pragma unroll
    for (int nt = 0; nt < 4; ++nt) o[mt][nt] = (f32x4_t){0.f, 0.f, 0.f, 0.f};
  f32x4_t ol[4];
#pragma unroll
  for (int mt = 0; mt < 4; ++mt) ol[mt] = (f32x4_t){0.f, 0.f, 0.f, 0.f};

  // staging: 64 rows x 64 shorts (128B); thread -> row kr, two 16B chunks
  const int kr = tid >> 2;
  const int kcb = tid & 3;
  const int kc = kcb * 16;
  const int r7 = kr & 7;
  const int st0 = kr * 64 + ((2 * kcb) ^ r7) * 8;
  const int st1 = kr * 64 + ((2 * kcb + 1) ^ r7) * 8;

  // frag-read offsets (per-lane constants, hoisted)
  const int rowb = m * 64;
  const int ck0 = rowb + ((quad ^ sw) * 8);         // K dk 0..31
  const int ck1 = rowb + (((quad + 4) ^ sw) * 8);   // K dk 32..63
  const int vq = quad >> 1, vo = (quad & 1) * 4;    // V sub-chunk
  const int va0[2] = { rowb + vo + (((0 + vq) ^ sw) * 8),
                       rowb + vo + (((4 + vq) ^ sw) * 8) };  // vf.h[0], c=0/1
  const int va1[2] = { rowb + vo + (((2 + vq) ^ sw) * 8),
                       rowb + vo + (((6 + vq) ^ sw) * 8) };  // vf.h[1], c=0/1

  // prologue: tile kt0 -> buf0; issue loads for kt0+1
  const unsigned short* kptr = kb + (size_t)(kt0 * 64 + kr) * NDK + kc;
  const unsigned short* vptr = vb + (size_t)kr * NL + kt0 * 64 + kc;
  uint4 pk0 = *(const uint4*)kptr;
  uint4 pk1 = *(const uint4*)(kptr + 8);
  uint4 pv0 = *(const uint4*)vptr;
  uint4 pv1 = *(const uint4*)(vptr + 8);
  *(uint4*)&Ks[0][st0] = pk0;
  *(uint4*)&Ks[0][st1] = pk1;
  *(uint4*)&Vt[0][st0] = pv0;
  *(uint4*)&Vt[0][st1] = pv1;
  kptr += 64 * NDK;
  vptr += 64;
  pk0 = *(const uint4*)kptr;
  pk1 = *(const uint4*)(kptr + 8);
  pv0 = *(const uint4*)vptr;
  pv1 = *(const uint4*)(vptr + 8);
  __syncthreads();

#define ATTN_STEP(B, W, KT)                                                   \
  {                                                                           \
    /* ---- all 32 QK MFMAs for BOTH c-blocks, into stage regs ---- */        \
    f32x4_t s[4][4];  /* [nt][mt] */                                          \
    _Pragma("unroll")                                                         \
    for (int nt = 0; nt < 4; ++nt) {                                          \
      const bf16x8_t kf0 = *(const bf16x8_t*)&Ks[B][nt * 1024 + ck0];         \
      const bf16x8_t kf1 = *(const bf16x8_t*)&Ks[B][nt * 1024 + ck1];         \
      _Pragma("unroll")                                                       \
      for (int mt = 0; mt < 4; ++mt) {                                        \
        f32x4_t s_ = (f32x4_t){0.f, 0.f, 0.f, 0.f};                           \
        s_ = __builtin_amdgcn_mfma_f32_16x16x32_bf16(kf0, aq[mt][0], s_, 0, 0, 0); \
        s_ = __builtin_amdgcn_mfma_f32_16x16x32_bf16(kf1, aq[mt][1], s_, 0, 0, 0); \
        s[nt][mt] = s_;                                                       \
      }                                                                       \
    }                                                                         \
    __builtin_amdgcn_sched_barrier(0);  /* pin: QK issued before exp phase */ \
    _Pragma("unroll")                                                         \
    for (int c = 0; c < 2; ++c) {                                             \
      union U { bf16x8_t v; unsigned d[4]; };                                 \
      U pa[4];                                                                \
      _Pragma("unroll")                                                       \
      for (int mt = 0; mt < 4; ++mt) {                                        \
        pa[mt].d[0] = cvt_pk_hw(__builtin_amdgcn_exp2f(s[2 * c][mt][0]),      \
                                __builtin_amdgcn_exp2f(s[2 * c][mt][1]));     \
        pa[mt].d[1] = cvt_pk_hw(__builtin_amdgcn_exp2f(s[2 * c][mt][2]),      \
                                __builtin_amdgcn_exp2f(s[2 * c][mt][3]));     \
        pa[mt].d[2] = cvt_pk_hw(__builtin_amdgcn_exp2f(s[2 * c + 1][mt][0]),  \
                                __builtin_amdgcn_exp2f(s[2 * c + 1][mt][1])); \
        pa[mt].d[3] = cvt_pk_hw(__builtin_amdgcn_exp2f(s[2 * c + 1][mt][2]),  \
                                __builtin_amdgcn_exp2f(s[2 * c + 1][mt][3])); \
      }                                                                       \
      __builtin_amdgcn_s_setprio(1);                                          \
      _Pragma("unroll")                                                       \
      for (int nt = 0; nt < 4; ++nt) {                                        \
        union { bf16x8_t v; uint2 h[2]; } vf;                                 \
        vf.h[0] = *(const uint2*)&Vt[B][nt * 1024 + va0[c]];                  \
        vf.h[1] = *(const uint2*)&Vt[B][nt * 1024 + va1[c]];                  \
        _Pragma("unroll")                                                     \
        for (int mt = 0; mt < 4; ++mt)                                        \
          o[mt][nt] = __builtin_amdgcn_mfma_f32_16x16x32_bf16(pa[mt].v, vf.v, \
                                                              o[mt][nt], 0, 0, 0); \
      }                                                                       \
      _Pragma("unroll")                                                       \
      for (int mt = 0; mt < 4; ++mt)                                          \
        ol[mt] = __builtin_amdgcn_mfma_f32_16x16x32_bf16(pa[mt].v, ones,      \
                                                         ol[mt], 0, 0, 0);    \
      __builtin_amdgcn_s_setprio(0);                                          \
    }                                                                         \
    if ((KT) + 1 < kt1) {                                                     \
      *(uint4*)&Ks[W][st0] = pk0;                                             \
      *(uint4*)&Ks[W][st1] = pk1;                                             \
      *(uint4*)&Vt[W][st0] = pv0;                                             \
      *(uint4*)&Vt[W][st1] = pv1;                                             \
      if ((KT) + 2 < kt1) {                                                   \
        kptr += 64 * NDK;                                                     \
        vptr += 64;                                                           \
        pk0 = *(const uint4*)kptr;                                            \
        pk1 = *(const uint4*)(kptr + 8);                                      \
        pv0 = *(const uint4*)vptr;                                            \
        pv1 = *(const uint4*)(vptr + 8);                                      \
      }                                                                       \
      __syncthreads();                                                        \
    }                                                                         \
  }

  for (int kt = kt0; kt < kt1; kt += 2) {
    ATTN_STEP(0, 1, kt);
    ATTN_STEP(1, 0, kt + 1);
  }
#undef ATTN_STEP

  const size_t pbase = (size_t)(half * 16 + bh) * NL;
#pragma unroll
  for (int mt = 0; mt < 4; ++mt) {
    const int q0 = qt * 256 + w * 64 + mt * 16 + quad * 4;
    if (m == 0)
      *(float4*)&lp[pbase + q0] =
          make_float4(ol[mt][0], ol[mt][1], ol[mt][2], ol[mt][3]);
#pragma unroll
    for (int r = 0; r < 4; ++r) {
      float* dst = op + (pbase + q0 + r) * NDK;
#pragma unroll
      for (int nt = 0; nt < 4; ++nt) dst[16 * nt + m] = o[mt][nt][r];
    }
  }
}

extern "C" void kernel_launch(void* const* d_in, const int* in_sizes, int n_in,
                              void* d_out, int out_size, void* d_ws, size_t ws_size,
                              hipStream_t stream)
{
  const float* q  = (const float*)d_in[0];
  const float* k  = (const float*)d_in[1];
  const float* v  = (const float*)d_in[2];
  const float* Wq = (const float*)d_in[3];
  const float* bq = (const float*)d_in[4];
  const float* Wk = (const float*)d_in[5];
  const float* bk = (const float*)d_in[6];
  const float* Wv = (const float*)d_in[7];
  const float* bv = (const float*)d_in[8];
  const float* Wo = (const float*)d_in[9];
  const float* bo = (const float*)d_in[10];

  const size_t PLANE = (size_t)NM * ND;               // 4.19M elems (8.39 MB bf16)
  unsigned short* wt = (unsigned short*)d_ws;         // 8 x 512KB weight planes (4 MB)
  unsigned short* qhp = wt + 8 * (size_t)ND * ND;     // 8 MB
  unsigned short* khp = qhp + PLANE;                  // 8 MB
  unsigned short* vtp = khp + PLANE;                  // 8 MB (transposed V, written by proj)
  float* op = (float*)(vtp + PLANE);                  // 33.55 MB fp32 partials
  float* lp = op + 2 * (size_t)16 * NL * NDK;         // 0.5 MB

  unsigned short* wth[4], *wtl[4];
  for (int i = 0; i < 4; ++i) {
    wth[i] = wt + (size_t)(2 * i) * ND * ND;
    wtl[i] = wt + (size_t)(2 * i + 1) * ND * ND;
  }

  // 1) transpose+split weight matrices
  WArgs wa;
  wa.W[0] = Wq; wa.W[1] = Wk; wa.W[2] = Wv; wa.W[3] = Wo;
  for (int i = 0; i < 4; ++i) { wa.Th[i] = wth[i]; wa.Tl[i] = wtl[i]; }
  wsplit_kernel<<<dim3(8, 8, 4), 256, 0, stream>>>(wa);

  // 2) three projection GEMMs reading fp32 q/k/v directly (round3 fused into
  //    the A-stage cvt); V writes transposed head layout directly
  ProjArgs pa;
  pa.A[0] = q; pa.A[1] = k; pa.A[2] = v;
  pa.Bh[0] = wth[0]; pa.Bl[0] = wtl[0];
  pa.Bh[1] = wth[1]; pa.Bl[1] = wtl[1];
  pa.Bh[2] = wth[2]; pa.Bl[2] = wtl[2];
  pa.bias[0] = bq; pa.bias[1] = bk; pa.bias[2] = bv;
  pa.out[0] = qhp; pa.out[1] = khp; pa.out[2] = vtp;
  pa.scale[0] = QSCALE; pa.scale[1] = 1.0f; pa.scale[2] = 1.0f;
  gemm_proj_kernel<<<dim3(NM / 128, ND / 128, 3), 256, 0, stream>>>(pa);

  // 3) attention, 2-way key split, 256-q blocks (512 blocks, 2/CU)
  attn_kernel<<<dim3(NB * NH * (NL / 256) * 2), 256, 0, stream>>>(qhp, khp, vtp, op, lp);

  // 4) output GEMM with fused merge (reads op/lp partials directly;
  //    3-term split, 128x64 tiles, fp32 out)
  gemm_out_kernel<<<dim3(NM / 128, ND / 64), 256, 0, stream>>>(
      op, lp, wth[3], wtl[3], bo, (float*)d_out);
}

// Round 12
// 243.613 us; speedup vs baseline: 1.3623x; 1.3623x over previous
//
#include <hip/hip_runtime.h>
#include <hip/hip_bf16.h>

#define NB 2
#define NL 4096
#define ND 512
#define NH 8
#define NDK 64
#define NM (NB * NL)   // 8192
#define QSCALE 0.18033688011112042f  // 0.125 * log2(e)

typedef short bf16x8_t __attribute__((ext_vector_type(8)));
typedef float f32x4_t __attribute__((ext_vector_type(4)));

// fp32 -> bf16 bits, round-to-nearest-even
static __device__ __forceinline__ unsigned short f2bs(float f) {
  union { float f; unsigned u; } c; c.f = f;
  unsigned r = c.u + 0x7fffu + ((c.u >> 16) & 1u);
  return (unsigned short)(r >> 16);
}
static __device__ __forceinline__ float bs2f(unsigned short s) {
  union { unsigned u; float f; } c; c.u = ((unsigned)s) << 16; return c.f;
}
static __device__ __forceinline__ unsigned pk_bf16(float a, float b) {
  union { __hip_bfloat162 h; unsigned u; } c;
  c.h = __float22bfloat162_rn(make_float2(a, b));
  return c.u;
}
// hardware packed f32->bf16 (RNE), single VOP3 instruction
static __device__ __forceinline__ unsigned cvt_pk_hw(float a, float b) {
  unsigned r;
  asm("v_cvt_pk_bf16_f32 %0, %1, %2" : "=v"(r) : "v"(a), "v"(b));
  return r;
}

// ---------- pre-pass: round q,k,v fp32 -> bf16 planes (one launch, y=3) ----------
__global__ __launch_bounds__(256)
void round3_kernel(const float* __restrict__ s0, const float* __restrict__ s1,
                   const float* __restrict__ s2, unsigned short* __restrict__ d0,
                   unsigned short* __restrict__ d1, unsigned short* __restrict__ d2)
{
  const float* s = blockIdx.y == 0 ? s0 : (blockIdx.y == 1 ? s1 : s2);
  unsigned short* d = blockIdx.y == 0 ? d0 : (blockIdx.y == 1 ? d1 : d2);
  const size_t i = ((size_t)blockIdx.x * 256 + threadIdx.x) * 8;
  const float4 f0 = *(const float4*)(s + i);
  const float4 f1 = *(const float4*)(s + i + 4);
  uint4 o;
  o.x = pk_bf16(f0.x, f0.y);
  o.y = pk_bf16(f0.z, f0.w);
  o.z = pk_bf16(f1.x, f1.y);
  o.w = pk_bf16(f1.z, f1.w);
  *(uint4*)(d + i) = o;
}

// ---------- pre-pass: W[k][n] fp32 -> transposed hi/lo bf16 planes [n][k] ----------
struct WArgs {
  const float* W[4];
  unsigned short* Th[4];
  unsigned short* Tl[4];
};
__global__ __launch_bounds__(256)
void wsplit_kernel(WArgs a)
{
  const int z = blockIdx.z;
  const float* __restrict__ W = a.W[z];
  const int tid = threadIdx.x;
  const int n = blockIdx.x * 64 + (tid & 63);
  const int kb = blockIdx.y * 64 + (tid >> 6) * 16;
  unsigned short h[16], l[16];
#pragma unroll
  for (int u = 0; u < 16; ++u) {
    const float x = W[(size_t)(kb + u) * ND + n];
    h[u] = f2bs(x);
    l[u] = f2bs(x - bs2f(h[u]));
  }
  unsigned wh[8], wl[8];
#pragma unroll
  for (int p = 0; p < 8; ++p) {
    wh[p] = (unsigned)h[2 * p] | ((unsigned)h[2 * p + 1] << 16);
    wl[p] = (unsigned)l[2 * p] | ((unsigned)l[2 * p + 1] << 16);
  }
  unsigned short* th = a.Th[z] + (size_t)n * ND + kb;
  unsigned short* tl = a.Tl[z] + (size_t)n * ND + kb;
  *(uint4*)th = make_uint4(wh[0], wh[1], wh[2], wh[3]);
  *(uint4*)(th + 8) = make_uint4(wh[4], wh[5], wh[6], wh[7]);
  *(uint4*)tl = make_uint4(wl[0], wl[1], wl[2], wl[3]);
  *(uint4*)(tl + 8) = make_uint4(wl[4], wl[5], wl[6], wl[7]);
}

// ---------- split-bf16 MFMA GEMM core, 128 x (NJ*16) tile, BK=32, reg prefetch ----------
// STATIC per-instantiation __shared__ arrays (addrspace(3) known to the
// compiler natively). R9-R11 showed: arena-pointer LDS (stores through a
// passed generic pointer) and gld_lds-forced unpadded layouts both regress;
// this static+padded+reg-staged form is the fastest measured.
// A: bf16 plane(s) [M][512]. B: transposed bf16 planes [n][k].
// ASPLIT: 3-term (Ahi.Bhi + Ahi.Blo + Alo.Bhi); else 2-term.
// OUTMODE: 0 = bf16 head layout [B][H][L][64] (LDS-bounced, coalesced);
//          1 = fp32 flat [M][512];
//          2 = bf16 transposed head layout [bh][d][l] (for V).
template <bool ASPLIT, int NJ, int OUTMODE>
__device__ __forceinline__ void gemm_core(
    const unsigned short* __restrict__ Ahi, const unsigned short* __restrict__ Alo,
    const unsigned short* __restrict__ Bh, const unsigned short* __restrict__ Bl,
    const float* __restrict__ bias, unsigned short* __restrict__ outH,
    float* __restrict__ outF, int m0, int n0, float scale)
{
  __shared__ unsigned short AH[128][36];
  __shared__ unsigned short AL[ASPLIT ? 128 : 1][36];
  __shared__ unsigned short BHs[NJ * 16][36];
  __shared__ unsigned short BLs[NJ * 16][36];

  const int tid = threadIdx.x;
  const int lane = tid & 63, w = tid >> 6;
  const int m = lane & 15, quad = lane >> 4;
  const int r = tid >> 1, hf = (tid & 1) * 16;
  const int rb = (NJ == 8) ? (tid >> 1) : (tid >> 2);
  const int cb = (NJ == 8) ? ((tid & 1) * 16) : ((tid & 3) * 8);

  const unsigned short* aRow = Ahi + (size_t)(m0 + r) * ND + hf;
  const unsigned short* alRow = ASPLIT ? (Alo + (size_t)(m0 + r) * ND + hf) : nullptr;
  const unsigned short* bhRow = Bh + (size_t)(n0 + rb) * ND + cb;
  const unsigned short* blRow = Bl + (size_t)(n0 + rb) * ND + cb;

  // prefetch k0 = 0
  uint4 ra0 = *(const uint4*)(aRow);
  uint4 ra1 = *(const uint4*)(aRow + 8);
  uint4 rl0, rl1;
  if constexpr (ASPLIT) {
    rl0 = *(const uint4*)(alRow);
    rl1 = *(const uint4*)(alRow + 8);
  }
  uint4 rbh0 = *(const uint4*)(bhRow);
  uint4 rbl0 = *(const uint4*)(blRow);
  uint4 rbh1, rbl1;
  if constexpr (NJ == 8) {
    rbh1 = *(const uint4*)(bhRow + 8);
    rbl1 = *(const uint4*)(blRow + 8);
  }

  f32x4_t acc[2][NJ];
#pragma unroll
  for (int i = 0; i < 2; ++i)
#pragma unroll
    for (int j = 0; j < NJ; ++j) acc[i][j] = (f32x4_t){0.f, 0.f, 0.f, 0.f};

  for (int k0 = 0; k0 < ND; k0 += 32) {
    __syncthreads();
    *(uint4*)&AH[r][hf] = ra0;
    *(uint4*)&AH[r][hf + 8] = ra1;
    if constexpr (ASPLIT) {
      *(uint4*)&AL[r][hf] = rl0;
      *(uint4*)&AL[r][hf + 8] = rl1;
    }
    *(uint4*)&BHs[rb][cb] = rbh0;
    *(uint4*)&BLs[rb][cb] = rbl0;
    if constexpr (NJ == 8) {
      *(uint4*)&BHs[rb][cb + 8] = rbh1;
      *(uint4*)&BLs[rb][cb + 8] = rbl1;
    }
    if (k0 + 32 < ND) {  // prefetch next K-slab (overlaps MFMA below)
      const int kn = k0 + 32;
      ra0 = *(const uint4*)(aRow + kn);
      ra1 = *(const uint4*)(aRow + kn + 8);
      if constexpr (ASPLIT) {
        rl0 = *(const uint4*)(alRow + kn);
        rl1 = *(const uint4*)(alRow + kn + 8);
      }
      rbh0 = *(const uint4*)(bhRow + kn);
      rbl0 = *(const uint4*)(blRow + kn);
      if constexpr (NJ == 8) {
        rbh1 = *(const uint4*)(bhRow + kn + 8);
        rbl1 = *(const uint4*)(blRow + kn + 8);
      }
    }
    __syncthreads();

    bf16x8_t ah[2], al[2];
#pragma unroll
    for (int i = 0; i < 2; ++i) {
      ah[i] = *(const bf16x8_t*)&AH[w * 32 + 16 * i + m][quad * 8];
      if constexpr (ASPLIT) al[i] = *(const bf16x8_t*)&AL[w * 32 + 16 * i + m][quad * 8];
    }
#pragma unroll
    for (int j = 0; j < NJ; ++j) {
      const bf16x8_t bhj = *(const bf16x8_t*)&BHs[16 * j + m][quad * 8];
      const bf16x8_t blj = *(const bf16x8_t*)&BLs[16 * j + m][quad * 8];
#pragma unroll
      for (int i = 0; i < 2; ++i) {
        acc[i][j] = __builtin_amdgcn_mfma_f32_16x16x32_bf16(ah[i], bhj, acc[i][j], 0, 0, 0);
        acc[i][j] = __builtin_amdgcn_mfma_f32_16x16x32_bf16(ah[i], blj, acc[i][j], 0, 0, 0);
        if constexpr (ASPLIT)
          acc[i][j] = __builtin_amdgcn_mfma_f32_16x16x32_bf16(al[i], bhj, acc[i][j], 0, 0, 0);
      }
    }
  }

  if constexpr (OUTMODE == 1) {
#pragma unroll
    for (int i = 0; i < 2; ++i)
#pragma unroll
      for (int rr = 0; rr < 4; ++rr) {
        const int mg = m0 + w * 32 + 16 * i + quad * 4 + rr;
#pragma unroll
        for (int j = 0; j < NJ; ++j) {
          const int n = n0 + 16 * j + m;
          outF[(size_t)mg * ND + n] = (acc[i][j][rr] + bias[n]) * scale;
        }
      }
  } else if constexpr (OUTMODE == 0) {
    // head-layout out: bounce through LDS (reuse BHs as T[32 l][136 n]) in
    // 4 passes of 32 l-rows; store coalesced uint4 runs along d.
    // acc indices remain compile-time (w==p only gates; no rule-20 hazard).
    unsigned short* T = &BHs[0][0];   // 32*136 = 4352 shorts <= 4608
    const int bb = m0 >> 12;
#pragma unroll 1
    for (int p = 0; p < 4; ++p) {
      __syncthreads();
      if (w == p) {
#pragma unroll
        for (int i = 0; i < 2; ++i)
#pragma unroll
          for (int j = 0; j < NJ; ++j) {
            const int n = 16 * j + m;
            const float bv = bias[n0 + n];
#pragma unroll
            for (int rr = 0; rr < 4; ++rr)
              T[(16 * i + quad * 4 + rr) * 136 + n] =
                  f2bs((acc[i][j][rr] + bv) * scale);
          }
      }
      __syncthreads();
      const int lr = tid >> 3;        // 0..31 local l-row
      const int seg = tid & 7;        // n-chunk of 16
      const uint4 t0 = *(const uint4*)&T[lr * 136 + seg * 16];
      const uint4 t1 = *(const uint4*)&T[lr * 136 + seg * 16 + 8];
      const int ng = n0 + seg * 16;
      const int h = ng >> 6, d = ng & (NDK - 1);
      const int l = (m0 + p * 32 + lr) & (NL - 1);
      unsigned short* dp = outH + (((size_t)(bb * NH + h)) * NL + l) * NDK + d;
      *(uint4*)dp = t0;
      *(uint4*)(dp + 8) = t1;
    }
  } else {
    // VTRANS: bounce through LDS (reuse BHs) in 4 passes of 32 l-rows,
    // store coalesced to [bh][d][l].
    unsigned short* T = &BHs[0][0];   // used as [128 n][34 shorts]
    const int bb = m0 >> 12;
    const int lbase = m0 & (NL - 1);
#pragma unroll 1
    for (int p = 0; p < 4; ++p) {
      __syncthreads();
      if (w == p) {
#pragma unroll
        for (int i = 0; i < 2; ++i)
#pragma unroll
          for (int j = 0; j < NJ; ++j) {
            const int n = 16 * j + m;
            const float bv = bias[n0 + n];
            const unsigned w0 = pk_bf16((acc[i][j][0] + bv) * scale,
                                        (acc[i][j][1] + bv) * scale);
            const unsigned w1 = pk_bf16((acc[i][j][2] + bv) * scale,
                                        (acc[i][j][3] + bv) * scale);
            *(uint2*)&T[n * 34 + 16 * i + quad * 4] = make_uint2(w0, w1);
          }
      }
      __syncthreads();
      const int n = tid >> 1;
      const int l0 = (tid & 1) * 16;
      const uint4 t0 = *(const uint4*)&T[n * 34 + l0];
      const uint4 t1 = *(const uint4*)&T[n * 34 + l0 + 8];
      const int ng = n0 + n;
      const int h = ng >> 6, d = ng & (NDK - 1);
      unsigned short* dp =
          outH + (((size_t)(bb * NH + h)) * NDK + d) * NL + lbase + 32 * p + l0;
      *(uint4*)dp = t0;
      *(uint4*)(dp + 8) = t1;
    }
  }
}

struct ProjArgs {
  const unsigned short* A[3];
  const unsigned short* Bh[3];
  const unsigned short* Bl[3];
  const float* bias[3];
  unsigned short* out[3];
  float scale[3];
};
__global__ __launch_bounds__(256, 3)
void gemm_proj_kernel(ProjArgs a)
{
  const int z = blockIdx.z;
  if (z < 2)
    gemm_core<false, 8, 0>(a.A[z], nullptr, a.Bh[z], a.Bl[z], a.bias[z], a.out[z],
                           nullptr, blockIdx.x * 128, blockIdx.y * 128, a.scale[z]);
  else
    gemm_core<false, 8, 2>(a.A[2], nullptr, a.Bh[2], a.Bl[2], a.bias[2], a.out[2],
                           nullptr, blockIdx.x * 128, blockIdx.y * 128, a.scale[2]);
}
__global__ __launch_bounds__(256, 3)
void gemm_out_kernel(const unsigned short* __restrict__ Ahi,
                     const unsigned short* __restrict__ Alo,
                     const unsigned short* __restrict__ Bh,
                     const unsigned short* __restrict__ Bl,
                     const float* __restrict__ bias, float* __restrict__ out)
{
  gemm_core<true, 4, 1>(Ahi, Alo, Bh, Bl, bias, nullptr, out,
                        blockIdx.x * 128, blockIdx.y * 64, 1.0f);
}

// ---------- MFMA bf16 flash attention ----------
// 256-q blocks (4 waves x 64 q), 2-way key-split, lane-local P via swapped
// QK^T + permuted MFMA contraction order over keys (no P LDS round-trip).
// DOUBLE-BUFFERED K/V LDS, one barrier per K-tile.
// SOFTWARE-PIPELINED c-blocks: ALL 32 QK MFMAs issued up front into stage
// regs s[4][4] (order pinned by sched_barrier), so exp2(c=0) overlaps the
// c=1 QK MFMAs and exp2(c=1) overlaps PV(c=0).
// Q pre-scaled by 0.125*log2(e) -> p = exp2(s) via raw v_exp_f32;
// P packing via hardware v_cvt_pk_bf16_f32. l-rowsums via ones-B MFMA.
// V arrives pre-transposed [bh][d][l].
// LDS: unpadded 128B rows + 16B-chunk XOR swizzle (chunk ^= row&7).
__global__ __launch_bounds__(256, 2)
void attn_kernel(const unsigned short* __restrict__ qh, const unsigned short* __restrict__ kh,
                 const unsigned short* __restrict__ vt_g, float* __restrict__ op,
                 float* __restrict__ lp)
{
  __shared__ unsigned short Ks[2][64 * 64];  // [key][d], swizzled
  __shared__ unsigned short Vt[2][64 * 64];  // [d][key], swizzled

  const int tid = threadIdx.x;
  const int w = tid >> 6;
  const int lane = tid & 63;
  const int m = lane & 15;
  const int quad = lane >> 4;
  const int sw = m & 7;                 // read-side swizzle key (row&7 = m&7)

  const int bid = blockIdx.x;
  const int half = bid & 1;
  const int qt = (bid >> 1) & 15;       // 16 q-tiles of 256
  const int bh = bid >> 5;              // b*NH + h
  const int kt0 = half * 32, kt1 = kt0 + 32;
  const unsigned short* qb = qh + (size_t)bh * NL * NDK;
  const unsigned short* kb = kh + (size_t)bh * NL * NDK;
  const unsigned short* vb = vt_g + (size_t)bh * NDK * NL;  // [d][l]

  // Q fragments: 64 q rows per wave (4 m-tiles of 16), held in registers.
  bf16x8_t aq[4][2];
#pragma unroll
  for (int mt = 0; mt < 4; ++mt) {
    const unsigned short* qsrc =
        qb + (size_t)(qt * 256 + w * 64 + mt * 16 + m) * NDK + quad * 8;
    aq[mt][0] = *(const bf16x8_t*)(qsrc);
    aq[mt][1] = *(const bf16x8_t*)(qsrc + 32);
  }

  const short ob = (short)0x3F80;
  const bf16x8_t ones = {ob, ob, ob, ob, ob, ob, ob, ob};

  f32x4_t o[4][4];
#pragma unroll
  for (int mt = 0; mt < 4; ++mt)
#pragma unroll
    for (int nt = 0; nt < 4; ++nt) o[mt][nt] = (f32x4_t){0.f, 0.f, 0.f, 0.f};
  f32x4_t ol[4];
#pragma unroll
  for (int mt = 0; mt < 4; ++mt) ol[mt] = (f32x4_t){0.f, 0.f, 0.f, 0.f};

  // staging: 64 rows x 64 shorts (128B); thread -> row kr, two 16B chunks
  const int kr = tid >> 2;
  const int kcb = tid & 3;
  const int kc = kcb * 16;
  const int r7 = kr & 7;
  const int st0 = kr * 64 + ((2 * kcb) ^ r7) * 8;
  const int st1 = kr * 64 + ((2 * kcb + 1) ^ r7) * 8;

  // frag-read offsets (per-lane constants, hoisted)
  const int rowb = m * 64;
  const int ck0 = rowb + ((quad ^ sw) * 8);         // K dk 0..31
  const int ck1 = rowb + (((quad + 4) ^ sw) * 8);   // K dk 32..63
  const int vq = quad >> 1, vo = (quad & 1) * 4;    // V sub-chunk
  const int va0[2] = { rowb + vo + (((0 + vq) ^ sw) * 8),
                       rowb + vo + (((4 + vq) ^ sw) * 8) };  // vf.h[0], c=0/1
  const int va1[2] = { rowb + vo + (((2 + vq) ^ sw) * 8),
                       rowb + vo + (((6 + vq) ^ sw) * 8) };  // vf.h[1], c=0/1

  // prologue: tile kt0 -> buf0; issue loads for kt0+1
  const unsigned short* kptr = kb + (size_t)(kt0 * 64 + kr) * NDK + kc;
  const unsigned short* vptr = vb + (size_t)kr * NL + kt0 * 64 + kc;
  uint4 pk0 = *(const uint4*)kptr;
  uint4 pk1 = *(const uint4*)(kptr + 8);
  uint4 pv0 = *(const uint4*)vptr;
  uint4 pv1 = *(const uint4*)(vptr + 8);
  *(uint4*)&Ks[0][st0] = pk0;
  *(uint4*)&Ks[0][st1] = pk1;
  *(uint4*)&Vt[0][st0] = pv0;
  *(uint4*)&Vt[0][st1] = pv1;
  kptr += 64 * NDK;
  vptr += 64;
  pk0 = *(const uint4*)kptr;
  pk1 = *(const uint4*)(kptr + 8);
  pv0 = *(const uint4*)vptr;
  pv1 = *(const uint4*)(vptr + 8);
  __syncthreads();

#define ATTN_STEP(B, W, KT)                                                   \
  {                                                                           \
    /* ---- all 32 QK MFMAs for BOTH c-blocks, into stage regs ---- */        \
    f32x4_t s[4][4];  /* [nt][mt] */                                          \
    _Pragma("unroll")                                                         \
    for (int nt = 0; nt < 4; ++nt) {                                          \
      const bf16x8_t kf0 = *(const bf16x8_t*)&Ks[B][nt * 1024 + ck0];         \
      const bf16x8_t kf1 = *(const bf16x8_t*)&Ks[B][nt * 1024 + ck1];         \
      _Pragma("unroll")                                                       \
      for (int mt = 0; mt < 4; ++mt) {                                        \
        f32x4_t s_ = (f32x4_t){0.f, 0.f, 0.f, 0.f};                           \
        s_ = __builtin_amdgcn_mfma_f32_16x16x32_bf16(kf0, aq[mt][0], s_, 0, 0, 0); \
        s_ = __builtin_amdgcn_mfma_f32_16x16x32_bf16(kf1, aq[mt][1], s_, 0, 0, 0); \
        s[nt][mt] = s_;                                                       \
      }                                                                       \
    }                                                                         \
    __builtin_amdgcn_sched_barrier(0);  /* pin: QK issued before exp phase */ \
    _Pragma("unroll")                                                         \
    for (int c = 0; c < 2; ++c) {                                             \
      union U { bf16x8_t v; unsigned d[4]; };                                 \
      U pa[4];                                                                \
      _Pragma("unroll")                                                       \
      for (int mt = 0; mt < 4; ++mt) {                                        \
        pa[mt].d[0] = cvt_pk_hw(__builtin_amdgcn_exp2f(s[2 * c][mt][0]),      \
                                __builtin_amdgcn_exp2f(s[2 * c][mt][1]));     \
        pa[mt].d[1] = cvt_pk_hw(__builtin_amdgcn_exp2f(s[2 * c][mt][2]),      \
                                __builtin_amdgcn_exp2f(s[2 * c][mt][3]));     \
        pa[mt].d[2] = cvt_pk_hw(__builtin_amdgcn_exp2f(s[2 * c + 1][mt][0]),  \
                                __builtin_amdgcn_exp2f(s[2 * c + 1][mt][1])); \
        pa[mt].d[3] = cvt_pk_hw(__builtin_amdgcn_exp2f(s[2 * c + 1][mt][2]),  \
                                __builtin_amdgcn_exp2f(s[2 * c + 1][mt][3])); \
      }                                                                       \
      __builtin_amdgcn_s_setprio(1);                                          \
      _Pragma("unroll")                                                       \
      for (int nt = 0; nt < 4; ++nt) {                                        \
        union { bf16x8_t v; uint2 h[2]; } vf;                                 \
        vf.h[0] = *(const uint2*)&Vt[B][nt * 1024 + va0[c]];                  \
        vf.h[1] = *(const uint2*)&Vt[B][nt * 1024 + va1[c]];                  \
        _Pragma("unroll")                                                     \
        for (int mt = 0; mt < 4; ++mt)                                        \
          o[mt][nt] = __builtin_amdgcn_mfma_f32_16x16x32_bf16(pa[mt].v, vf.v, \
                                                              o[mt][nt], 0, 0, 0); \
      }                                                                       \
      _Pragma("unroll")                                                       \
      for (int mt = 0; mt < 4; ++mt)                                          \
        ol[mt] = __builtin_amdgcn_mfma_f32_16x16x32_bf16(pa[mt].v, ones,      \
                                                         ol[mt], 0, 0, 0);    \
      __builtin_amdgcn_s_setprio(0);                                          \
    }                                                                         \
    if ((KT) + 1 < kt1) {                                                     \
      *(uint4*)&Ks[W][st0] = pk0;                                             \
      *(uint4*)&Ks[W][st1] = pk1;                                             \
      *(uint4*)&Vt[W][st0] = pv0;                                             \
      *(uint4*)&Vt[W][st1] = pv1;                                             \
      if ((KT) + 2 < kt1) {                                                   \
        kptr += 64 * NDK;                                                     \
        vptr += 64;                                                           \
        pk0 = *(const uint4*)kptr;                                            \
        pk1 = *(const uint4*)(kptr + 8);                                      \
        pv0 = *(const uint4*)vptr;                                            \
        pv1 = *(const uint4*)(vptr + 8);                                      \
      }                                                                       \
      __syncthreads();                                                        \
    }                                                                         \
  }

  for (int kt = kt0; kt < kt1; kt += 2) {
    ATTN_STEP(0, 1, kt);
    ATTN_STEP(1, 0, kt + 1);
  }
#undef ATTN_STEP

  const size_t pbase = (size_t)(half * 16 + bh) * NL;
#pragma unroll
  for (int mt = 0; mt < 4; ++mt) {
    const int q0 = qt * 256 + w * 64 + mt * 16 + quad * 4;
    if (m == 0)
      *(float4*)&lp[pbase + q0] =
          make_float4(ol[mt][0], ol[mt][1], ol[mt][2], ol[mt][3]);
#pragma unroll
    for (int r = 0; r < 4; ++r) {
      float* dst = op + (pbase + q0 + r) * NDK;
#pragma unroll
      for (int nt = 0; nt < 4; ++nt) dst[16 * nt + m] = o[mt][nt][r];
    }
  }
}

// ---------- merge: ctx = (o0+o1)/(l0+l1), emit split-bf16 planes ----------
__global__ __launch_bounds__(256)
void merge_kernel(const float* __restrict__ op, const float* __restrict__ lp,
                  unsigned short* __restrict__ ctxh, unsigned short* __restrict__ ctxl)
{
  const size_t t = (size_t)blockIdx.x * 256 + threadIdx.x;
  const int d0 = (int)(t & 7) * 8;
  const size_t row = t >> 3;               // bh*NL + l
  const float l0 = lp[row];
  const float l1 = lp[row + (size_t)16 * NL];
  const float inv = 1.0f / (l0 + l1);
  const float* a = op + row * NDK + d0;
  const float* c = a + (size_t)16 * NL * NDK;
  const float4 a0 = *(const float4*)a, a1 = *(const float4*)(a + 4);
  const float4 c0 = *(const float4*)c, c1 = *(const float4*)(c + 4);
  const float x[8] = {(a0.x + c0.x) * inv, (a0.y + c0.y) * inv,
                      (a0.z + c0.z) * inv, (a0.w + c0.w) * inv,
                      (a1.x + c1.x) * inv, (a1.y + c1.y) * inv,
                      (a1.z + c1.z) * inv, (a1.w + c1.w) * inv};
  unsigned short hs[8], ls[8];
#pragma unroll
  for (int u = 0; u < 8; ++u) {
    hs[u] = f2bs(x[u]);
    ls[u] = f2bs(x[u] - bs2f(hs[u]));
  }
  const int bh = (int)(row >> 12), l = (int)(row & (NL - 1));
  const int b = bh >> 3, h = bh & 7;
  const size_t dst = ((size_t)(b * NL + l)) * ND + h * 64 + d0;
  uint4 uh, ul;
  uh.x = (unsigned)hs[0] | ((unsigned)hs[1] << 16);
  uh.y = (unsigned)hs[2] | ((unsigned)hs[3] << 16);
  uh.z = (unsigned)hs[4] | ((unsigned)hs[5] << 16);
  uh.w = (unsigned)hs[6] | ((unsigned)hs[7] << 16);
  ul.x = (unsigned)ls[0] | ((unsigned)ls[1] << 16);
  ul.y = (unsigned)ls[2] | ((unsigned)ls[3] << 16);
  ul.z = (unsigned)ls[4] | ((unsigned)ls[5] << 16);
  ul.w = (unsigned)ls[6] | ((unsigned)ls[7] << 16);
  *(uint4*)(ctxh + dst) = uh;
  *(uint4*)(ctxl + dst) = ul;
}

extern "C" void kernel_launch(void* const* d_in, const int* in_sizes, int n_in,
                              void* d_out, int out_size, void* d_ws, size_t ws_size,
                              hipStream_t stream)
{
  const float* q  = (const float*)d_in[0];
  const float* k  = (const float*)d_in[1];
  const float* v  = (const float*)d_in[2];
  const float* Wq = (const float*)d_in[3];
  const float* bq = (const float*)d_in[4];
  const float* Wk = (const float*)d_in[5];
  const float* bk = (const float*)d_in[6];
  const float* Wv = (const float*)d_in[7];
  const float* bv = (const float*)d_in[8];
  const float* Wo = (const float*)d_in[9];
  const float* bo = (const float*)d_in[10];

  const size_t PLANE = (size_t)NM * ND;               // 4.19M elems (8.39 MB bf16)
  unsigned short* wt = (unsigned short*)d_ws;         // 8 x 512KB weight planes (4 MB)
  unsigned short* qhp = wt + 8 * (size_t)ND * ND;     // 8 MB
  unsigned short* khp = qhp + PLANE;                  // 8 MB
  unsigned short* vtp = khp + PLANE;                  // 8 MB (transposed V, written by proj)
  float* op = (float*)(vtp + PLANE);                  // 33.55 MB fp32 partials
  float* lp = op + 2 * (size_t)16 * NL * NDK;         // 0.5 MB
  // aliases inside op region (all dead before attn writes op):
  unsigned short* qb = (unsigned short*)op;           // round3 out / proj in
  unsigned short* kb = qb + PLANE;
  unsigned short* vb = kb + PLANE;
  unsigned short* ctxh = qhp;                         // merge out (qhp dead after attn)
  unsigned short* ctxl = khp;

  unsigned short* wth[4], *wtl[4];
  for (int i = 0; i < 4; ++i) {
    wth[i] = wt + (size_t)(2 * i) * ND * ND;
    wtl[i] = wt + (size_t)(2 * i + 1) * ND * ND;
  }

  // 1) round q,k,v to bf16 planes
  round3_kernel<<<dim3(PLANE / (256 * 8), 3), 256, 0, stream>>>(q, k, v, qb, kb, vb);

  // 2) transpose+split weight matrices
  WArgs wa;
  wa.W[0] = Wq; wa.W[1] = Wk; wa.W[2] = Wv; wa.W[3] = Wo;
  for (int i = 0; i < 4; ++i) { wa.Th[i] = wth[i]; wa.Tl[i] = wtl[i]; }
  wsplit_kernel<<<dim3(8, 8, 4), 256, 0, stream>>>(wa);

  // 3) three projection GEMMs; V writes transposed head layout directly
  ProjArgs pa;
  pa.A[0] = qb; pa.A[1] = kb; pa.A[2] = vb;
  pa.Bh[0] = wth[0]; pa.Bl[0] = wtl[0];
  pa.Bh[1] = wth[1]; pa.Bl[1] = wtl[1];
  pa.Bh[2] = wth[2]; pa.Bl[2] = wtl[2];
  pa.bias[0] = bq; pa.bias[1] = bk; pa.bias[2] = bv;
  pa.out[0] = qhp; pa.out[1] = khp; pa.out[2] = vtp;
  pa.scale[0] = QSCALE; pa.scale[1] = 1.0f; pa.scale[2] = 1.0f;
  gemm_proj_kernel<<<dim3(NM / 128, ND / 128, 3), 256, 0, stream>>>(pa);

  // 4) attention, 2-way key split, 256-q blocks (512 blocks, 2/CU)
  attn_kernel<<<dim3(NB * NH * (NL / 256) * 2), 256, 0, stream>>>(qhp, khp, vtp, op, lp);

  // 5) merge partials -> split-bf16 ctx planes
  merge_kernel<<<dim3((16 * NL * NDK) / (256 * 8)), 256, 0, stream>>>(op, lp, ctxh, ctxl);

  // 6) output GEMM (3-term split, 128x64 tiles, fp32 out)
  gemm_out_kernel<<<dim3(NM / 128, ND / 64), 256, 0, stream>>>(
      ctxh, ctxl, wth[3], wtl[3], bo, (float*)d_out);
}

// Round 13
// 240.535 us; speedup vs baseline: 1.3798x; 1.0128x over previous
//
#include <hip/hip_runtime.h>
#include <hip/hip_bf16.h>

#define NB 2
#define NL 4096
#define ND 512
#define NH 8
#define NDK 64
#define NM (NB * NL)   // 8192
#define QSCALE 0.18033688011112042f  // 0.125 * log2(e)

typedef short bf16x8_t __attribute__((ext_vector_type(8)));
typedef float f32x4_t __attribute__((ext_vector_type(4)));

// fp32 -> bf16 bits, round-to-nearest-even
static __device__ __forceinline__ unsigned short f2bs(float f) {
  union { float f; unsigned u; } c; c.f = f;
  unsigned r = c.u + 0x7fffu + ((c.u >> 16) & 1u);
  return (unsigned short)(r >> 16);
}
static __device__ __forceinline__ float bs2f(unsigned short s) {
  union { unsigned u; float f; } c; c.u = ((unsigned)s) << 16; return c.f;
}
static __device__ __forceinline__ unsigned pk_bf16(float a, float b) {
  union { __hip_bfloat162 h; unsigned u; } c;
  c.h = __float22bfloat162_rn(make_float2(a, b));
  return c.u;
}
// hardware packed f32->bf16 (RNE), single VOP3 instruction
static __device__ __forceinline__ unsigned cvt_pk_hw(float a, float b) {
  unsigned r;
  asm("v_cvt_pk_bf16_f32 %0, %1, %2" : "=v"(r) : "v"(a), "v"(b));
  return r;
}

// ---------- pre-pass: round q,k,v fp32 -> bf16 planes (one launch, y=3) ----------
__global__ __launch_bounds__(256)
void round3_kernel(const float* __restrict__ s0, const float* __restrict__ s1,
                   const float* __restrict__ s2, unsigned short* __restrict__ d0,
                   unsigned short* __restrict__ d1, unsigned short* __restrict__ d2)
{
  const float* s = blockIdx.y == 0 ? s0 : (blockIdx.y == 1 ? s1 : s2);
  unsigned short* d = blockIdx.y == 0 ? d0 : (blockIdx.y == 1 ? d1 : d2);
  const size_t i = ((size_t)blockIdx.x * 256 + threadIdx.x) * 8;
  const float4 f0 = *(const float4*)(s + i);
  const float4 f1 = *(const float4*)(s + i + 4);
  uint4 o;
  o.x = pk_bf16(f0.x, f0.y);
  o.y = pk_bf16(f0.z, f0.w);
  o.z = pk_bf16(f1.x, f1.y);
  o.w = pk_bf16(f1.z, f1.w);
  *(uint4*)(d + i) = o;
}

// ---------- pre-pass: W[k][n] fp32 -> transposed hi/lo bf16 planes [n][k] ----------
struct WArgs {
  const float* W[4];
  unsigned short* Th[4];
  unsigned short* Tl[4];
};
__global__ __launch_bounds__(256)
void wsplit_kernel(WArgs a)
{
  const int z = blockIdx.z;
  const float* __restrict__ W = a.W[z];
  const int tid = threadIdx.x;
  const int n = blockIdx.x * 64 + (tid & 63);
  const int kb = blockIdx.y * 64 + (tid >> 6) * 16;
  unsigned short h[16], l[16];
#pragma unroll
  for (int u = 0; u < 16; ++u) {
    const float x = W[(size_t)(kb + u) * ND + n];
    h[u] = f2bs(x);
    l[u] = f2bs(x - bs2f(h[u]));
  }
  unsigned wh[8], wl[8];
#pragma unroll
  for (int p = 0; p < 8; ++p) {
    wh[p] = (unsigned)h[2 * p] | ((unsigned)h[2 * p + 1] << 16);
    wl[p] = (unsigned)l[2 * p] | ((unsigned)l[2 * p + 1] << 16);
  }
  unsigned short* th = a.Th[z] + (size_t)n * ND + kb;
  unsigned short* tl = a.Tl[z] + (size_t)n * ND + kb;
  *(uint4*)th = make_uint4(wh[0], wh[1], wh[2], wh[3]);
  *(uint4*)(th + 8) = make_uint4(wh[4], wh[5], wh[6], wh[7]);
  *(uint4*)tl = make_uint4(wl[0], wl[1], wl[2], wl[3]);
  *(uint4*)(tl + 8) = make_uint4(wl[4], wl[5], wl[6], wl[7]);
}

// ---------- split-bf16 MFMA GEMM core, 128 x (NJ*16) tile, BK=32, reg prefetch ----------
// STATIC per-instantiation __shared__ arrays (addrspace(3) known natively).
// R9-R11: arena-pointer LDS and gld_lds-forced unpadded layouts both regress.
// R13: OUTMODE 3 = runtime (block-uniform) epilogue select between head-layout
// (0) and VTRANS (2) -- collapses proj's two instantiations into ONE, halving
// its static LDS (55296 -> 27720 B) and doubling proj occupancy, with no
// pointer indirection and all acc indices still compile-time.
// A: bf16 plane(s) [M][512]. B: transposed bf16 planes [n][k].
// ASPLIT: 3-term (Ahi.Bhi + Ahi.Blo + Alo.Bhi); else 2-term.
// OUTMODE: 0 = bf16 head layout [B][H][L][64]; 1 = fp32 flat [M][512];
//          2 = bf16 transposed head layout [bh][d][l] (for V);
//          3 = runtime select 0/2 via vtrans flag.
template <bool ASPLIT, int NJ, int OUTMODE>
__device__ __forceinline__ void gemm_core(
    const unsigned short* __restrict__ Ahi, const unsigned short* __restrict__ Alo,
    const unsigned short* __restrict__ Bh, const unsigned short* __restrict__ Bl,
    const float* __restrict__ bias, unsigned short* __restrict__ outH,
    float* __restrict__ outF, int m0, int n0, float scale, int vtrans = 0)
{
  __shared__ unsigned short AH[128][36];
  __shared__ unsigned short AL[ASPLIT ? 128 : 1][36];
  __shared__ unsigned short BHs[NJ * 16][36];
  __shared__ unsigned short BLs[NJ * 16][36];

  const int tid = threadIdx.x;
  const int lane = tid & 63, w = tid >> 6;
  const int m = lane & 15, quad = lane >> 4;
  const int r = tid >> 1, hf = (tid & 1) * 16;
  const int rb = (NJ == 8) ? (tid >> 1) : (tid >> 2);
  const int cb = (NJ == 8) ? ((tid & 1) * 16) : ((tid & 3) * 8);

  const unsigned short* aRow = Ahi + (size_t)(m0 + r) * ND + hf;
  const unsigned short* alRow = ASPLIT ? (Alo + (size_t)(m0 + r) * ND + hf) : nullptr;
  const unsigned short* bhRow = Bh + (size_t)(n0 + rb) * ND + cb;
  const unsigned short* blRow = Bl + (size_t)(n0 + rb) * ND + cb;

  // prefetch k0 = 0
  uint4 ra0 = *(const uint4*)(aRow);
  uint4 ra1 = *(const uint4*)(aRow + 8);
  uint4 rl0, rl1;
  if constexpr (ASPLIT) {
    rl0 = *(const uint4*)(alRow);
    rl1 = *(const uint4*)(alRow + 8);
  }
  uint4 rbh0 = *(const uint4*)(bhRow);
  uint4 rbl0 = *(const uint4*)(blRow);
  uint4 rbh1, rbl1;
  if constexpr (NJ == 8) {
    rbh1 = *(const uint4*)(bhRow + 8);
    rbl1 = *(const uint4*)(blRow + 8);
  }

  f32x4_t acc[2][NJ];
#pragma unroll
  for (int i = 0; i < 2; ++i)
#pragma unroll
    for (int j = 0; j < NJ; ++j) acc[i][j] = (f32x4_t){0.f, 0.f, 0.f, 0.f};

  for (int k0 = 0; k0 < ND; k0 += 32) {
    __syncthreads();
    *(uint4*)&AH[r][hf] = ra0;
    *(uint4*)&AH[r][hf + 8] = ra1;
    if constexpr (ASPLIT) {
      *(uint4*)&AL[r][hf] = rl0;
      *(uint4*)&AL[r][hf + 8] = rl1;
    }
    *(uint4*)&BHs[rb][cb] = rbh0;
    *(uint4*)&BLs[rb][cb] = rbl0;
    if constexpr (NJ == 8) {
      *(uint4*)&BHs[rb][cb + 8] = rbh1;
      *(uint4*)&BLs[rb][cb + 8] = rbl1;
    }
    if (k0 + 32 < ND) {  // prefetch next K-slab (overlaps MFMA below)
      const int kn = k0 + 32;
      ra0 = *(const uint4*)(aRow + kn);
      ra1 = *(const uint4*)(aRow + kn + 8);
      if constexpr (ASPLIT) {
        rl0 = *(const uint4*)(alRow + kn);
        rl1 = *(const uint4*)(alRow + kn + 8);
      }
      rbh0 = *(const uint4*)(bhRow + kn);
      rbl0 = *(const uint4*)(blRow + kn);
      if constexpr (NJ == 8) {
        rbh1 = *(const uint4*)(bhRow + kn + 8);
        rbl1 = *(const uint4*)(blRow + kn + 8);
      }
    }
    __syncthreads();

    bf16x8_t ah[2], al[2];
#pragma unroll
    for (int i = 0; i < 2; ++i) {
      ah[i] = *(const bf16x8_t*)&AH[w * 32 + 16 * i + m][quad * 8];
      if constexpr (ASPLIT) al[i] = *(const bf16x8_t*)&AL[w * 32 + 16 * i + m][quad * 8];
    }
#pragma unroll
    for (int j = 0; j < NJ; ++j) {
      const bf16x8_t bhj = *(const bf16x8_t*)&BHs[16 * j + m][quad * 8];
      const bf16x8_t blj = *(const bf16x8_t*)&BLs[16 * j + m][quad * 8];
#pragma unroll
      for (int i = 0; i < 2; ++i) {
        acc[i][j] = __builtin_amdgcn_mfma_f32_16x16x32_bf16(ah[i], bhj, acc[i][j], 0, 0, 0);
        acc[i][j] = __builtin_amdgcn_mfma_f32_16x16x32_bf16(ah[i], blj, acc[i][j], 0, 0, 0);
        if constexpr (ASPLIT)
          acc[i][j] = __builtin_amdgcn_mfma_f32_16x16x32_bf16(al[i], bhj, acc[i][j], 0, 0, 0);
      }
    }
  }

  if constexpr (OUTMODE == 1) {
#pragma unroll
    for (int i = 0; i < 2; ++i)
#pragma unroll
      for (int rr = 0; rr < 4; ++rr) {
        const int mg = m0 + w * 32 + 16 * i + quad * 4 + rr;
#pragma unroll
        for (int j = 0; j < NJ; ++j) {
          const int n = n0 + 16 * j + m;
          outF[(size_t)mg * ND + n] = (acc[i][j][rr] + bias[n]) * scale;
        }
      }
  } else if (OUTMODE == 0 || (OUTMODE == 3 && !vtrans)) {
    // head-layout out: bounce through LDS (reuse BHs as T[32 l][136 n]) in
    // 4 passes of 32 l-rows; store coalesced uint4 runs along d.
    // acc indices remain compile-time (w==p only gates; no rule-20 hazard).
    unsigned short* T = &BHs[0][0];   // 32*136 = 4352 shorts <= 4608
    const int bb = m0 >> 12;
#pragma unroll 1
    for (int p = 0; p < 4; ++p) {
      __syncthreads();
      if (w == p) {
#pragma unroll
        for (int i = 0; i < 2; ++i)
#pragma unroll
          for (int j = 0; j < NJ; ++j) {
            const int n = 16 * j + m;
            const float bv = bias[n0 + n];
#pragma unroll
            for (int rr = 0; rr < 4; ++rr)
              T[(16 * i + quad * 4 + rr) * 136 + n] =
                  f2bs((acc[i][j][rr] + bv) * scale);
          }
      }
      __syncthreads();
      const int lr = tid >> 3;        // 0..31 local l-row
      const int seg = tid & 7;        // n-chunk of 16
      const uint4 t0 = *(const uint4*)&T[lr * 136 + seg * 16];
      const uint4 t1 = *(const uint4*)&T[lr * 136 + seg * 16 + 8];
      const int ng = n0 + seg * 16;
      const int h = ng >> 6, d = ng & (NDK - 1);
      const int l = (m0 + p * 32 + lr) & (NL - 1);
      unsigned short* dp = outH + (((size_t)(bb * NH + h)) * NL + l) * NDK + d;
      *(uint4*)dp = t0;
      *(uint4*)(dp + 8) = t1;
    }
  } else if (OUTMODE == 2 || OUTMODE == 3) {
    // VTRANS: bounce through LDS (reuse BHs) in 4 passes of 32 l-rows,
    // store coalesced to [bh][d][l].
    unsigned short* T = &BHs[0][0];   // used as [128 n][34 shorts]
    const int bb = m0 >> 12;
    const int lbase = m0 & (NL - 1);
#pragma unroll 1
    for (int p = 0; p < 4; ++p) {
      __syncthreads();
      if (w == p) {
#pragma unroll
        for (int i = 0; i < 2; ++i)
#pragma unroll
          for (int j = 0; j < NJ; ++j) {
            const int n = 16 * j + m;
            const float bv = bias[n0 + n];
            const unsigned w0 = pk_bf16((acc[i][j][0] + bv) * scale,
                                        (acc[i][j][1] + bv) * scale);
            const unsigned w1 = pk_bf16((acc[i][j][2] + bv) * scale,
                                        (acc[i][j][3] + bv) * scale);
            *(uint2*)&T[n * 34 + 16 * i + quad * 4] = make_uint2(w0, w1);
          }
      }
      __syncthreads();
      const int n = tid >> 1;
      const int l0 = (tid & 1) * 16;
      const uint4 t0 = *(const uint4*)&T[n * 34 + l0];
      const uint4 t1 = *(const uint4*)&T[n * 34 + l0 + 8];
      const int ng = n0 + n;
      const int h = ng >> 6, d = ng & (NDK - 1);
      unsigned short* dp =
          outH + (((size_t)(bb * NH + h)) * NDK + d) * NL + lbase + 32 * p + l0;
      *(uint4*)dp = t0;
      *(uint4*)(dp + 8) = t1;
    }
  }
}

struct ProjArgs {
  const unsigned short* A[3];
  const unsigned short* Bh[3];
  const unsigned short* Bl[3];
  const float* bias[3];
  unsigned short* out[3];
  float scale[3];
};
// SINGLE instantiation (OUTMODE 3, runtime vtrans) -> one set of static LDS
// arrays (27720 B) instead of two summed (55296 B): proj occupancy 2 -> 4
// blocks/CU with QK and V blocks co-resident.
__global__ __launch_bounds__(256, 3)
void gemm_proj_kernel(ProjArgs a)
{
  const int z = blockIdx.z;
  gemm_core<false, 8, 3>(a.A[z], nullptr, a.Bh[z], a.Bl[z], a.bias[z], a.out[z],
                         nullptr, blockIdx.x * 128, blockIdx.y * 128, a.scale[z],
                         z == 2);
}
__global__ __launch_bounds__(256, 3)
void gemm_out_kernel(const unsigned short* __restrict__ Ahi,
                     const unsigned short* __restrict__ Alo,
                     const unsigned short* __restrict__ Bh,
                     const unsigned short* __restrict__ Bl,
                     const float* __restrict__ bias, float* __restrict__ out)
{
  gemm_core<true, 4, 1>(Ahi, Alo, Bh, Bl, bias, nullptr, out,
                        blockIdx.x * 128, blockIdx.y * 64, 1.0f);
}

// ---------- MFMA bf16 flash attention ----------
// 256-q blocks (4 waves x 64 q), 2-way key-split, lane-local P via swapped
// QK^T + permuted MFMA contraction order over keys (no P LDS round-trip).
// DOUBLE-BUFFERED K/V LDS, one barrier per K-tile.
// SOFTWARE-PIPELINED c-blocks: ALL 32 QK MFMAs issued up front into stage
// regs s[4][4] (order pinned by sched_barrier), so exp2(c=0) overlaps the
// c=1 QK MFMAs and exp2(c=1) overlaps PV(c=0).
// Q pre-scaled by 0.125*log2(e) -> p = exp2(s) via raw v_exp_f32;
// P packing via hardware v_cvt_pk_bf16_f32. l-rowsums via ones-B MFMA.
// V arrives pre-transposed [bh][d][l].
// LDS: unpadded 128B rows + 16B-chunk XOR swizzle (chunk ^= row&7).
__global__ __launch_bounds__(256, 2)
void attn_kernel(const unsigned short* __restrict__ qh, const unsigned short* __restrict__ kh,
                 const unsigned short* __restrict__ vt_g, float* __restrict__ op,
                 float* __restrict__ lp)
{
  __shared__ unsigned short Ks[2][64 * 64];  // [key][d], swizzled
  __shared__ unsigned short Vt[2][64 * 64];  // [d][key], swizzled

  const int tid = threadIdx.x;
  const int w = tid >> 6;
  const int lane = tid & 63;
  const int m = lane & 15;
  const int quad = lane >> 4;
  const int sw = m & 7;                 // read-side swizzle key (row&7 = m&7)

  const int bid = blockIdx.x;
  const int half = bid & 1;
  const int qt = (bid >> 1) & 15;       // 16 q-tiles of 256
  const int bh = bid >> 5;              // b*NH + h
  const int kt0 = half * 32, kt1 = kt0 + 32;
  const unsigned short* qb = qh + (size_t)bh * NL * NDK;
  const unsigned short* kb = kh + (size_t)bh * NL * NDK;
  const unsigned short* vb = vt_g + (size_t)bh * NDK * NL;  // [d][l]

  // Q fragments: 64 q rows per wave (4 m-tiles of 16), held in registers.
  bf16x8_t aq[4][2];
#pragma unroll
  for (int mt = 0; mt < 4; ++mt) {
    const unsigned short* qsrc =
        qb + (size_t)(qt * 256 + w * 64 + mt * 16 + m) * NDK + quad * 8;
    aq[mt][0] = *(const bf16x8_t*)(qsrc);
    aq[mt][1] = *(const bf16x8_t*)(qsrc + 32);
  }

  const short ob = (short)0x3F80;
  const bf16x8_t ones = {ob, ob, ob, ob, ob, ob, ob, ob};

  f32x4_t o[4][4];
#pragma unroll
  for (int mt = 0; mt < 4; ++mt)
#pragma unroll
    for (int nt = 0; nt < 4; ++nt) o[mt][nt] = (f32x4_t){0.f, 0.f, 0.f, 0.f};
  f32x4_t ol[4];
#pragma unroll
  for (int mt = 0; mt < 4; ++mt) ol[mt] = (f32x4_t){0.f, 0.f, 0.f, 0.f};

  // staging: 64 rows x 64 shorts (128B); thread -> row kr, two 16B chunks
  const int kr = tid >> 2;
  const int kcb = tid & 3;
  const int kc = kcb * 16;
  const int r7 = kr & 7;
  const int st0 = kr * 64 + ((2 * kcb) ^ r7) * 8;
  const int st1 = kr * 64 + ((2 * kcb + 1) ^ r7) * 8;

  // frag-read offsets (per-lane constants, hoisted)
  const int rowb = m * 64;
  const int ck0 = rowb + ((quad ^ sw) * 8);         // K dk 0..31
  const int ck1 = rowb + (((quad + 4) ^ sw) * 8);   // K dk 32..63
  const int vq = quad >> 1, vo = (quad & 1) * 4;    // V sub-chunk
  const int va0[2] = { rowb + vo + (((0 + vq) ^ sw) * 8),
                       rowb + vo + (((4 + vq) ^ sw) * 8) };  // vf.h[0], c=0/1
  const int va1[2] = { rowb + vo + (((2 + vq) ^ sw) * 8),
                       rowb + vo + (((6 + vq) ^ sw) * 8) };  // vf.h[1], c=0/1

  // prologue: tile kt0 -> buf0; issue loads for kt0+1
  const unsigned short* kptr = kb + (size_t)(kt0 * 64 + kr) * NDK + kc;
  const unsigned short* vptr = vb + (size_t)kr * NL + kt0 * 64 + kc;
  uint4 pk0 = *(const uint4*)kptr;
  uint4 pk1 = *(const uint4*)(kptr + 8);
  uint4 pv0 = *(const uint4*)vptr;
  uint4 pv1 = *(const uint4*)(vptr + 8);
  *(uint4*)&Ks[0][st0] = pk0;
  *(uint4*)&Ks[0][st1] = pk1;
  *(uint4*)&Vt[0][st0] = pv0;
  *(uint4*)&Vt[0][st1] = pv1;
  kptr += 64 * NDK;
  vptr += 64;
  pk0 = *(const uint4*)kptr;
  pk1 = *(const uint4*)(kptr + 8);
  pv0 = *(const uint4*)vptr;
  pv1 = *(const uint4*)(vptr + 8);
  __syncthreads();

#define ATTN_STEP(B, W, KT)                                                   \
  {                                                                           \
    /* ---- all 32 QK MFMAs for BOTH c-blocks, into stage regs ---- */        \
    f32x4_t s[4][4];  /* [nt][mt] */                                          \
    _Pragma("unroll")                                                         \
    for (int nt = 0; nt < 4; ++nt) {                                          \
      const bf16x8_t kf0 = *(const bf16x8_t*)&Ks[B][nt * 1024 + ck0];         \
      const bf16x8_t kf1 = *(const bf16x8_t*)&Ks[B][nt * 1024 + ck1];         \
      _Pragma("unroll")                                                       \
      for (int mt = 0; mt < 4; ++mt) {                                        \
        f32x4_t s_ = (f32x4_t){0.f, 0.f, 0.f, 0.f};                           \
        s_ = __builtin_amdgcn_mfma_f32_16x16x32_bf16(kf0, aq[mt][0], s_, 0, 0, 0); \
        s_ = __builtin_amdgcn_mfma_f32_16x16x32_bf16(kf1, aq[mt][1], s_, 0, 0, 0); \
        s[nt][mt] = s_;                                                       \
      }                                                                       \
    }                                                                         \
    __builtin_amdgcn_sched_barrier(0);  /* pin: QK issued before exp phase */ \
    _Pragma("unroll")                                                         \
    for (int c = 0; c < 2; ++c) {                                             \
      union U { bf16x8_t v; unsigned d[4]; };                                 \
      U pa[4];                                                                \
      _Pragma("unroll")                                                       \
      for (int mt = 0; mt < 4; ++mt) {                                        \
        pa[mt].d[0] = cvt_pk_hw(__builtin_amdgcn_exp2f(s[2 * c][mt][0]),      \
                                __builtin_amdgcn_exp2f(s[2 * c][mt][1]));     \
        pa[mt].d[1] = cvt_pk_hw(__builtin_amdgcn_exp2f(s[2 * c][mt][2]),      \
                                __builtin_amdgcn_exp2f(s[2 * c][mt][3]));     \
        pa[mt].d[2] = cvt_pk_hw(__builtin_amdgcn_exp2f(s[2 * c + 1][mt][0]),  \
                                __builtin_amdgcn_exp2f(s[2 * c + 1][mt][1])); \
        pa[mt].d[3] = cvt_pk_hw(__builtin_amdgcn_exp2f(s[2 * c + 1][mt][2]),  \
                                __builtin_amdgcn_exp2f(s[2 * c + 1][mt][3])); \
      }                                                                       \
      __builtin_amdgcn_s_setprio(1);                                          \
      _Pragma("unroll")                                                       \
      for (int nt = 0; nt < 4; ++nt) {                                        \
        union { bf16x8_t v; uint2 h[2]; } vf;                                 \
        vf.h[0] = *(const uint2*)&Vt[B][nt * 1024 + va0[c]];                  \
        vf.h[1] = *(const uint2*)&Vt[B][nt * 1024 + va1[c]];                  \
        _Pragma("unroll")                                                     \
        for (int mt = 0; mt < 4; ++mt)                                        \
          o[mt][nt] = __builtin_amdgcn_mfma_f32_16x16x32_bf16(pa[mt].v, vf.v, \
                                                              o[mt][nt], 0, 0, 0); \
      }                                                                       \
      _Pragma("unroll")                                                       \
      for (int mt = 0; mt < 4; ++mt)                                          \
        ol[mt] = __builtin_amdgcn_mfma_f32_16x16x32_bf16(pa[mt].v, ones,      \
                                                         ol[mt], 0, 0, 0);    \
      __builtin_amdgcn_s_setprio(0);                                          \
    }                                                                         \
    if ((KT) + 1 < kt1) {                                                     \
      *(uint4*)&Ks[W][st0] = pk0;                                             \
      *(uint4*)&Ks[W][st1] = pk1;                                             \
      *(uint4*)&Vt[W][st0] = pv0;                                             \
      *(uint4*)&Vt[W][st1] = pv1;                                             \
      if ((KT) + 2 < kt1) {                                                   \
        kptr += 64 * NDK;                                                     \
        vptr += 64;                                                           \
        pk0 = *(const uint4*)kptr;                                            \
        pk1 = *(const uint4*)(kptr + 8);                                      \
        pv0 = *(const uint4*)vptr;                                            \
        pv1 = *(const uint4*)(vptr + 8);                                      \
      }                                                                       \
      __syncthreads();                                                        \
    }                                                                         \
  }

  for (int kt = kt0; kt < kt1; kt += 2) {
    ATTN_STEP(0, 1, kt);
    ATTN_STEP(1, 0, kt + 1);
  }
#undef ATTN_STEP

  const size_t pbase = (size_t)(half * 16 + bh) * NL;
#pragma unroll
  for (int mt = 0; mt < 4; ++mt) {
    const int q0 = qt * 256 + w * 64 + mt * 16 + quad * 4;
    if (m == 0)
      *(float4*)&lp[pbase + q0] =
          make_float4(ol[mt][0], ol[mt][1], ol[mt][2], ol[mt][3]);
#pragma unroll
    for (int r = 0; r < 4; ++r) {
      float* dst = op + (pbase + q0 + r) * NDK;
#pragma unroll
      for (int nt = 0; nt < 4; ++nt) dst[16 * nt + m] = o[mt][nt][r];
    }
  }
}

// ---------- merge: ctx = (o0+o1)/(l0+l1), emit split-bf16 planes ----------
__global__ __launch_bounds__(256)
void merge_kernel(const float* __restrict__ op, const float* __restrict__ lp,
                  unsigned short* __restrict__ ctxh, unsigned short* __restrict__ ctxl)
{
  const size_t t = (size_t)blockIdx.x * 256 + threadIdx.x;
  const int d0 = (int)(t & 7) * 8;
  const size_t row = t >> 3;               // bh*NL + l
  const float l0 = lp[row];
  const float l1 = lp[row + (size_t)16 * NL];
  const float inv = 1.0f / (l0 + l1);
  const float* a = op + row * NDK + d0;
  const float* c = a + (size_t)16 * NL * NDK;
  const float4 a0 = *(const float4*)a, a1 = *(const float4*)(a + 4);
  const float4 c0 = *(const float4*)c, c1 = *(const float4*)(c + 4);
  const float x[8] = {(a0.x + c0.x) * inv, (a0.y + c0.y) * inv,
                      (a0.z + c0.z) * inv, (a0.w + c0.w) * inv,
                      (a1.x + c1.x) * inv, (a1.y + c1.y) * inv,
                      (a1.z + c1.z) * inv, (a1.w + c1.w) * inv};
  unsigned short hs[8], ls[8];
#pragma unroll
  for (int u = 0; u < 8; ++u) {
    hs[u] = f2bs(x[u]);
    ls[u] = f2bs(x[u] - bs2f(hs[u]));
  }
  const int bh = (int)(row >> 12), l = (int)(row & (NL - 1));
  const int b = bh >> 3, h = bh & 7;
  const size_t dst = ((size_t)(b * NL + l)) * ND + h * 64 + d0;
  uint4 uh, ul;
  uh.x = (unsigned)hs[0] | ((unsigned)hs[1] << 16);
  uh.y = (unsigned)hs[2] | ((unsigned)hs[3] << 16);
  uh.z = (unsigned)hs[4] | ((unsigned)hs[5] << 16);
  uh.w = (unsigned)hs[6] | ((unsigned)hs[7] << 16);
  ul.x = (unsigned)ls[0] | ((unsigned)ls[1] << 16);
  ul.y = (unsigned)ls[2] | ((unsigned)ls[3] << 16);
  ul.z = (unsigned)ls[4] | ((unsigned)ls[5] << 16);
  ul.w = (unsigned)ls[6] | ((unsigned)ls[7] << 16);
  *(uint4*)(ctxh + dst) = uh;
  *(uint4*)(ctxl + dst) = ul;
}

extern "C" void kernel_launch(void* const* d_in, const int* in_sizes, int n_in,
                              void* d_out, int out_size, void* d_ws, size_t ws_size,
                              hipStream_t stream)
{
  const float* q  = (const float*)d_in[0];
  const float* k  = (const float*)d_in[1];
  const float* v  = (const float*)d_in[2];
  const float* Wq = (const float*)d_in[3];
  const float* bq = (const float*)d_in[4];
  const float* Wk = (const float*)d_in[5];
  const float* bk = (const float*)d_in[6];
  const float* Wv = (const float*)d_in[7];
  const float* bv = (const float*)d_in[8];
  const float* Wo = (const float*)d_in[9];
  const float* bo = (const float*)d_in[10];

  const size_t PLANE = (size_t)NM * ND;               // 4.19M elems (8.39 MB bf16)
  unsigned short* wt = (unsigned short*)d_ws;         // 8 x 512KB weight planes (4 MB)
  unsigned short* qhp = wt + 8 * (size_t)ND * ND;     // 8 MB
  unsigned short* khp = qhp + PLANE;                  // 8 MB
  unsigned short* vtp = khp + PLANE;                  // 8 MB (transposed V, written by proj)
  float* op = (float*)(vtp + PLANE);                  // 33.55 MB fp32 partials
  float* lp = op + 2 * (size_t)16 * NL * NDK;         // 0.5 MB
  // aliases inside op region (all dead before attn writes op):
  unsigned short* qb = (unsigned short*)op;           // round3 out / proj in
  unsigned short* kb = qb + PLANE;
  unsigned short* vb = kb + PLANE;
  unsigned short* ctxh = qhp;                         // merge out (qhp dead after attn)
  unsigned short* ctxl = khp;

  unsigned short* wth[4], *wtl[4];
  for (int i = 0; i < 4; ++i) {
    wth[i] = wt + (size_t)(2 * i) * ND * ND;
    wtl[i] = wt + (size_t)(2 * i + 1) * ND * ND;
  }

  // 1) round q,k,v to bf16 planes
  round3_kernel<<<dim3(PLANE / (256 * 8), 3), 256, 0, stream>>>(q, k, v, qb, kb, vb);

  // 2) transpose+split weight matrices
  WArgs wa;
  wa.W[0] = Wq; wa.W[1] = Wk; wa.W[2] = Wv; wa.W[3] = Wo;
  for (int i = 0; i < 4; ++i) { wa.Th[i] = wth[i]; wa.Tl[i] = wtl[i]; }
  wsplit_kernel<<<dim3(8, 8, 4), 256, 0, stream>>>(wa);

  // 3) three projection GEMMs (single instantiation, runtime epilogue);
  //    V writes transposed head layout directly
  ProjArgs pa;
  pa.A[0] = qb; pa.A[1] = kb; pa.A[2] = vb;
  pa.Bh[0] = wth[0]; pa.Bl[0] = wtl[0];
  pa.Bh[1] = wth[1]; pa.Bl[1] = wtl[1];
  pa.Bh[2] = wth[2]; pa.Bl[2] = wtl[2];
  pa.bias[0] = bq; pa.bias[1] = bk; pa.bias[2] = bv;
  pa.out[0] = qhp; pa.out[1] = khp; pa.out[2] = vtp;
  pa.scale[0] = QSCALE; pa.scale[1] = 1.0f; pa.scale[2] = 1.0f;
  gemm_proj_kernel<<<dim3(NM / 128, ND / 128, 3), 256, 0, stream>>>(pa);

  // 4) attention, 2-way key split, 256-q blocks (512 blocks, 2/CU)
  attn_kernel<<<dim3(NB * NH * (NL / 256) * 2), 256, 0, stream>>>(qhp, khp, vtp, op, lp);

  // 5) merge partials -> split-bf16 ctx planes
  merge_kernel<<<dim3((16 * NL * NDK) / (256 * 8)), 256, 0, stream>>>(op, lp, ctxh, ctxl);

  // 6) output GEMM (3-term split, 128x64 tiles, fp32 out)
  gemm_out_kernel<<<dim3(NM / 128, ND / 64), 256, 0, stream>>>(
      ctxh, ctxl, wth[3], wtl[3], bo, (float*)d_out);
}